// Round 10
// baseline (97.875 us; speedup 1.0000x reference)
//
#include <hip/hip_runtime.h>
#include <hip/hip_bf16.h>

// Problem constants (fixed-shape problem)
#define BB   32
#define NREL 512
#define DD   1024
#define MTOT (BB * NREL)      // 16384
#define OBJ_ROWS (BB * 100)   // 3200

typedef __attribute__((ext_vector_type(8))) short bf16x8;
typedef __attribute__((ext_vector_type(4))) float f32x4;

__device__ __forceinline__ unsigned short f2bf(float f) {
    union { float f; unsigned u; } v; v.f = f;
    unsigned r = v.u + 0x7fff + ((v.u >> 16) & 1);   // RNE
    return (unsigned short)(r >> 16);
}

__device__ __forceinline__ float bf2f(unsigned short s) {
    union { unsigned u; float f; } v; v.u = (unsigned)s << 16;
    return v.f;
}

__device__ __forceinline__ void gld16(const void* g, void* l) {
    __builtin_amdgcn_global_load_lds(
        (const __attribute__((address_space(1))) unsigned int*)g,
        (__attribute__((address_space(3))) unsigned int*)l,
        16, 0, 0);
}

// raw barrier with compiler code-motion fences (no vmcnt drain, unlike __syncthreads)
__device__ __forceinline__ void barfence() {
    asm volatile("" ::: "memory");
    __builtin_amdgcn_s_barrier();
    asm volatile("" ::: "memory");
}

// ---- fused prep kernel: block-range partitioned, all branches block-uniform ----
// [0,1024):     ctxpart: part[s][b][n] = sum_{k in slice s} ctx[b][k]*W1[1024+k][n]
// [1024,2048):  wconv W1 top half -> W1t (bf16, N-major)
// [2048,3072):  wconv W2          -> W2t
// [3072,5120):  copy obj -> out_obj (fp32) AND obj -> obj_bf (bf16), one pass
__global__ void __launch_bounds__(256) prep_kernel(
    const float* __restrict__ obj, const float* __restrict__ ctx,
    const float* __restrict__ W1, const float* __restrict__ W2,
    unsigned short* __restrict__ W1t, unsigned short* __restrict__ W2t,
    float* __restrict__ part, unsigned short* __restrict__ obj_bf,
    float* __restrict__ out_obj) {
    __shared__ float smem[32 * 33];
    int bid = blockIdx.x;
    int tid = threadIdx.x;

    if (bid < 1024) {
        // ---- ctxpart: 32 b x 8 n-chunks x 4 k-slices; per-thread 128 k-iters ----
        int slice = bid & 3, chunk = (bid >> 2) & 7, b = bid >> 5;
        int nl = tid & 127, kh = tid >> 7;
        int n = chunk * 128 + nl;
        int kbase = slice * 256 + kh * 128;
        const float* c = ctx + (size_t)b * DD + kbase;
        const float* w = W1 + (size_t)(DD + kbase) * DD + n;
        float a0 = 0.f, a1 = 0.f, a2 = 0.f, a3 = 0.f;
#pragma unroll 8
        for (int k = 0; k < 128; k += 4) {
            a0 = fmaf(c[k + 0], w[(size_t)(k + 0) * DD], a0);
            a1 = fmaf(c[k + 1], w[(size_t)(k + 1) * DD], a1);
            a2 = fmaf(c[k + 2], w[(size_t)(k + 2) * DD], a2);
            a3 = fmaf(c[k + 3], w[(size_t)(k + 3) * DD], a3);
        }
        smem[kh * 128 + nl] = (a0 + a1) + (a2 + a3);
        __syncthreads();
        if (kh == 0)
            part[(((size_t)slice * BB + b) << 10) + n] = smem[nl] + smem[128 + nl];
    } else if (bid < 3072) {
        // ---- wconv: 32x32 transpose tiles, fp32 -> bf16 N-major ----
        const float* W = (bid < 2048) ? W1 : W2;
        unsigned short* Wt = (bid < 2048) ? W1t : W2t;
        int t = (bid - 1024) & 1023;
        int k0 = (t >> 5) * 32, n0 = (t & 31) * 32;
        int tr = tid >> 5, tc = tid & 31;
#pragma unroll
        for (int i = 0; i < 4; i++)
            smem[(tr + i * 8) * 33 + tc] = W[(size_t)(k0 + tr + i * 8) * DD + n0 + tc];
        __syncthreads();
#pragma unroll
        for (int i = 0; i < 4; i++)
            Wt[(size_t)(n0 + tr + i * 8) * DD + k0 + tc] = f2bf(smem[tc * 33 + tr + i * 8]);
    } else {
        // ---- copy + bf16-convert: 3200*1024 floats = 819200 float4, one read ----
        const float4* src = (const float4*)obj;
        float4* dst = (float4*)out_obj;
        ushort4* dbf = (ushort4*)obj_bf;
        for (int i = (bid - 3072) * 256 + tid; i < OBJ_ROWS * DD / 4; i += 2048 * 256) {
            float4 v = src[i];
            dst[i] = v;
            ushort4 o;
            o.x = f2bf(v.x); o.y = f2bf(v.y); o.z = f2bf(v.z); o.w = f2bf(v.w);
            dbf[i] = o;
        }
    }
}

// ---- gemmP: P = obj_bf @ W1t (blocks [0,400): 64x128 tile, BK=32, 4 waves)
//      + cbias tail blocks [400,432): cbias[b][n] = b1[n] + sum_s part[s][b][n]
// A [3200][1024] bf16 row-major; Bt [1024][1024] bf16 N-major. Out: P bf16.
__global__ void __launch_bounds__(256) gemmP_kernel(
    const unsigned short* __restrict__ A,
    const unsigned short* __restrict__ Bt,
    unsigned short* __restrict__ P,
    const float* __restrict__ part,
    const float* __restrict__ b1,
    float* __restrict__ cbias) {
    constexpr int K = 1024;
    __shared__ __attribute__((aligned(16))) unsigned short As[64 * 32];    // 4 KB
    __shared__ __attribute__((aligned(16))) unsigned short Bs[128 * 32];   // 8 KB
    int bid = blockIdx.x;
    int tid = threadIdx.x;

    if (bid >= 400) {
        // ---- cbias: one block per batch b ----
        int b = bid - 400;
        float4 v = ((const float4*)b1)[tid];
#pragma unroll
        for (int s = 0; s < 4; s++) {
            float4 p = ((const float4*)(part + (((size_t)s * BB + b) << 10)))[tid];
            v.x += p.x; v.y += p.y; v.z += p.z; v.w += p.w;
        }
        ((float4*)(cbias + ((size_t)b << 10)))[tid] = v;
        return;
    }

    int lane = tid & 63, wave = tid >> 6;
    int wr = wave >> 1, wc = wave & 1;      // 2 M-waves x 2 N-waves
    int mBase = (bid >> 3) * 64;            // 50 m-tiles
    int nBase = (bid & 7) * 128;            // 8 n-tiles

    f32x4 acc[2][4];
#pragma unroll
    for (int i = 0; i < 2; i++)
#pragma unroll
        for (int j = 0; j < 4; j++) acc[i][j] = (f32x4){0.f, 0.f, 0.f, 0.f};

    const unsigned short* Ab = A + (size_t)mBase * K;
    const unsigned short* Bb = Bt + (size_t)nBase * K;

    int arow = tid >> 2, akc = (tid & 3) * 8;

    for (int k0 = 0; k0 < K; k0 += 32) {
        gld16(Ab + (size_t)arow * K + k0 + akc, As + tid * 8);
#pragma unroll
        for (int hh = 0; hh < 2; hh++) {
            int c = tid + hh * 256;
            int row = c >> 2, kc = (c & 3) * 8;
            gld16(Bb + (size_t)row * K + k0 + kc, Bs + c * 8);
        }
        __syncthreads();
        int lr = lane & 15, kg = (lane >> 4) * 8;
        bf16x8 af[2], bfr[4];
#pragma unroll
        for (int m = 0; m < 2; m++)
            af[m] = *(const bf16x8*)&As[(wr * 32 + m * 16 + lr) * 32 + kg];
#pragma unroll
        for (int n = 0; n < 4; n++)
            bfr[n] = *(const bf16x8*)&Bs[(wc * 64 + n * 16 + lr) * 32 + kg];
#pragma unroll
        for (int m = 0; m < 2; m++)
#pragma unroll
            for (int n = 0; n < 4; n++)
                acc[m][n] = __builtin_amdgcn_mfma_f32_16x16x32_bf16(af[m], bfr[n], acc[m][n], 0, 0, 0);
        __syncthreads();
    }

    int lr = lane & 15, rg = (lane >> 4) * 4;
#pragma unroll
    for (int m = 0; m < 2; m++)
#pragma unroll
        for (int n = 0; n < 4; n++) {
            int col = nBase + wc * 64 + n * 16 + lr;
#pragma unroll
            for (int r = 0; r < 4; r++) {
                int row = mBase + wr * 32 + m * 16 + rg + r;
                P[(size_t)row * DD + col] = f2bf(acc[m][n][r]);
            }
        }
}

// ---- gemm2f: out = relu(h @ W2t + b2) with h computed ON THE FLY from P:
//      h[row][k] = relu(0.5*(P[i0][k]+P[i1][k]) + cbias[b][k])  (elementwise in k)
// Round-3 256x256/BK64/8-wave skeleton; B-path gld16 + inverse-XOR source.
// A-path reg-gather from L2-resident P. FIX vs round 8: ALOAD+BSTAGE for tile
// kt+1 issue BEFORE COMPUTE(kt) -> all 12 loads hide under the ~2700cy MFMA
// phase; vmcnt(0) after compute is then a cheap drain (T14 issue-early).
__global__ void __launch_bounds__(512, 2) gemm2f_kernel(
    const unsigned short* __restrict__ P,
    const int* __restrict__ pairs,
    const int* __restrict__ num_obj,
    const float* __restrict__ cbias,
    const unsigned short* __restrict__ Bt,
    const float* __restrict__ bias,
    float* __restrict__ Cout) {
    constexpr int K = 1024;
    constexpr int NT = K / 64;   // 16 K-tiles
    extern __shared__ unsigned short lds[];
    int tid = threadIdx.x;
    int lane = tid & 63, wave = tid >> 6;
    int wr = wave >> 2, wc = wave & 3;      // 2 M-waves x 4 N-waves
    int lr = lane & 15, g = lane >> 4;

    // XCD-aware swizzle: 256 blocks, 8 XCDs -> 32 contiguous tiles per XCD (8m x 4n)
    int wg = blockIdx.x;
    int swz = (wg & 7) * 32 + (wg >> 3);
    int mBase = (swz >> 2) * 256;
    int nBase = (swz & 3) * 256;

    int b = mBase >> 9;                     // all 256 rows in one batch
    int off = 0;
    for (int i = 0; i < b; i++) off += num_obj[i];
    const float* cbb = cbias + ((size_t)b << 10);

    const unsigned short* Bb = Bt + (size_t)nBase * K;

    // Staging pattern: slot s (16B units) holds source chunk (row=s>>3, c=(s&7)^(row&7)).
    int srow[4], soff[4], sdst[4];
    const unsigned short* pA[4];
    const unsigned short* pB[4];
#pragma unroll
    for (int i = 0; i < 4; i++) {
        int s = i * 512 + tid;              // 0..2047
        int row = s >> 3, cperm = s & 7;
        srow[i] = row;
        soff[i] = (cperm ^ (row & 7)) * 8;  // source element offset within K-slice
        sdst[i] = s * 8;                    // linear LDS dest (elements)
        int grow = mBase + row;
        pA[i] = P + (size_t)(pairs[2 * grow] + off) * DD + soff[i];
        pB[i] = P + (size_t)(pairs[2 * grow + 1] + off) * DD + soff[i];
    }

    f32x4 acc[8][4];
#pragma unroll
    for (int i = 0; i < 8; i++)
#pragma unroll
        for (int j = 0; j < 4; j++) acc[i][j] = (f32x4){0.f, 0.f, 0.f, 0.f};

    bf16x8 ra0[4], ra1[4];

    auto BSTAGE = [&](int bi, int kt) {
        unsigned short* Bd = lds + 32768 + bi * 16384;
        int ko = kt * 64;
#pragma unroll
        for (int i = 0; i < 4; i++)
            gld16(Bb + (size_t)srow[i] * K + ko + soff[i], Bd + sdst[i]);
    };

    auto ALOAD = [&](int kt) {
#pragma unroll
        for (int i = 0; i < 4; i++) {
            ra0[i] = *(const bf16x8*)(pA[i] + kt * 64);
            ra1[i] = *(const bf16x8*)(pB[i] + kt * 64);
        }
    };

    auto AWRITE = [&](int bi, int kt) {
        unsigned short* Ad = lds + bi * 16384;
#pragma unroll
        for (int i = 0; i < 4; i++) {
            const float* cp = cbb + kt * 64 + soff[i];
            float4 c0 = ((const float4*)cp)[0];
            float4 c1 = ((const float4*)cp)[1];
            float cc[8] = {c0.x, c0.y, c0.z, c0.w, c1.x, c1.y, c1.z, c1.w};
            bf16x8 o;
#pragma unroll
            for (int e = 0; e < 8; e++) {
                float v = 0.5f * (bf2f((unsigned short)ra0[i][e]) +
                                  bf2f((unsigned short)ra1[i][e])) + cc[e];
                v = v > 0.f ? v : 0.f;
                o[e] = (short)f2bf(v);
            }
            *(bf16x8*)(Ad + sdst[i]) = o;   // ds_write_b128, 16B-aligned
        }
    };

    auto COMPUTE = [&](int bi) {
        const unsigned short* As = lds + bi * 16384;
        const unsigned short* Bs = lds + 32768 + bi * 16384;
        bf16x8 bfr[4][2];
#pragma unroll
        for (int n = 0; n < 4; n++)
#pragma unroll
            for (int kk = 0; kk < 2; kk++) {
                int row = wc * 64 + n * 16 + lr;
                int c = kk * 4 + g;
                bfr[n][kk] = *(const bf16x8*)&Bs[row * 64 + ((c ^ (row & 7)) * 8)];
            }
#pragma unroll
        for (int half = 0; half < 2; half++) {
            bf16x8 af[4][2];
#pragma unroll
            for (int m = 0; m < 4; m++)
#pragma unroll
                for (int kk = 0; kk < 2; kk++) {
                    int row = wr * 128 + (half * 4 + m) * 16 + lr;
                    int c = kk * 4 + g;
                    af[m][kk] = *(const bf16x8*)&As[row * 64 + ((c ^ (row & 7)) * 8)];
                }
            __builtin_amdgcn_s_setprio(1);
#pragma unroll
            for (int m = 0; m < 4; m++)
#pragma unroll
                for (int n = 0; n < 4; n++)
#pragma unroll
                    for (int kk = 0; kk < 2; kk++)
                        acc[half * 4 + m][n] = __builtin_amdgcn_mfma_f32_16x16x32_bf16(
                            af[m][kk], bfr[n][kk], acc[half * 4 + m][n], 0, 0, 0);
            __builtin_amdgcn_s_setprio(0);
        }
    };

    // prologue: fully stage tile 0 into buf0
    ALOAD(0);
    BSTAGE(0, 0);
    asm volatile("s_waitcnt vmcnt(0)" ::: "memory");
    AWRITE(0, 0);
    asm volatile("s_waitcnt lgkmcnt(0)" ::: "memory");
    barfence();

    int cur = 0;
    for (int kt = 0; kt < NT; ++kt) {
        // issue next tile's loads BEFORE compute: 4 B glds -> LDS, 8 A gathers -> regs.
        // They have the whole MFMA phase (~2700 cy) to land.
        if (kt + 1 < NT) {
            BSTAGE(cur ^ 1, kt + 1);
            ALOAD(kt + 1);
        }
        COMPUTE(cur);
        asm volatile("s_waitcnt vmcnt(0)" ::: "memory");      // cheap drain now
        if (kt + 1 < NT)
            AWRITE(cur ^ 1, kt + 1);                          // combine + ds_write
        asm volatile("s_waitcnt lgkmcnt(0)" ::: "memory");    // ds_writes visible
        barfence();
        cur ^= 1;
    }

    // epilogue: bias + ReLU + fp32 store
    int rg = g * 4;
#pragma unroll
    for (int m = 0; m < 8; m++) {
#pragma unroll
        for (int n = 0; n < 4; n++) {
            int col = nBase + wc * 64 + n * 16 + lr;
            float bv = bias[col];
#pragma unroll
            for (int r = 0; r < 4; r++) {
                int row = mBase + wr * 128 + m * 16 + rg + r;
                float v = acc[m][n][r] + bv;
                Cout[(size_t)row * 1024 + col] = v > 0.f ? v : 0.f;
            }
        }
    }
}

extern "C" void kernel_launch(void* const* d_in, const int* in_sizes, int n_in,
                              void* d_out, int out_size, void* d_ws, size_t ws_size,
                              hipStream_t stream) {
    (void)in_sizes; (void)n_in; (void)out_size; (void)ws_size;
    const float* obj     = (const float*)d_in[0];
    const float* ctx     = (const float*)d_in[1];
    const int*   num_obj = (const int*)d_in[2];
    // d_in[3] = num_rels (unused by reference math)
    const int*   pairs   = (const int*)d_in[4];
    const float* W1      = (const float*)d_in[5];
    const float* b1      = (const float*)d_in[6];
    const float* W2      = (const float*)d_in[7];
    const float* b2      = (const float*)d_in[8];

    char* ws = (char*)d_ws;
    unsigned short* obj_bf = (unsigned short*)(ws);               // 6,553,600 B
    unsigned short* P      = (unsigned short*)(ws + 6553600);     // 6,553,600 B
    float*          cbias  = (float*)(ws + 13107200);             // 131,072 B
    unsigned short* W1t    = (unsigned short*)(ws + 46661632);    // 2,097,152 B
    unsigned short* W2t    = (unsigned short*)(ws + 48758784);    // 2,097,152 B

    float* out_obj = (float*)d_out;
    float* out_f   = out_obj + (size_t)OBJ_ROWS * DD;
    // ctx partial planes [4][32][1024] f32 (512 KB) live in out_f's head:
    // written by prep, read by gemmP's cbias blocks, then fully overwritten by
    // gemm2f (strict same-stream ordering; deterministic every call).
    float* part    = out_f;

    // allow 128 KiB dynamic LDS (host-side, not stream-ordered; graph-capture-safe)
    hipFuncSetAttribute(reinterpret_cast<const void*>(gemm2f_kernel),
                        hipFuncAttributeMaxDynamicSharedMemorySize, 131072);

    // 1) fused prep: ctxpart + wconv x2 + (copy obj -> out_obj & obj_bf)
    prep_kernel<<<dim3(5120), 256, 0, stream>>>(
        obj, ctx, W1, W2, W1t, W2t, part, obj_bf, out_obj);
    // 2) P = obj_bf @ W1_top  (400 blocks) + cbias reduce (32 blocks)
    gemmP_kernel<<<dim3(432), 256, 0, stream>>>(obj_bf, W1t, P, part, b1, cbias);
    // 3) out = relu(h(P,pairs,cbias) @ W2 + b2), h formed in-staging
    gemm2f_kernel<<<dim3(256), 512, 131072, stream>>>(
        P, pairs, num_obj, cbias, W2t, b2, out_f);
}

// Round 11
// 90.070 us; speedup vs baseline: 1.0867x; 1.0867x over previous
//
#include <hip/hip_runtime.h>
#include <hip/hip_bf16.h>

// Problem constants (fixed-shape problem)
#define BB   32
#define NREL 512
#define DD   1024
#define MTOT (BB * NREL)      // 16384
#define OBJ_ROWS (BB * 100)   // 3200

typedef __attribute__((ext_vector_type(8))) short bf16x8;
typedef __attribute__((ext_vector_type(4))) float f32x4;

__device__ __forceinline__ unsigned short f2bf(float f) {
    union { float f; unsigned u; } v; v.f = f;
    unsigned r = v.u + 0x7fff + ((v.u >> 16) & 1);   // RNE
    return (unsigned short)(r >> 16);
}

__device__ __forceinline__ float bf2f(unsigned short s) {
    union { unsigned u; float f; } v; v.u = (unsigned)s << 16;
    return v.f;
}

__device__ __forceinline__ void gld16(const void* g, void* l) {
    __builtin_amdgcn_global_load_lds(
        (const __attribute__((address_space(1))) unsigned int*)g,
        (__attribute__((address_space(3))) unsigned int*)l,
        16, 0, 0);
}

// raw barrier with compiler code-motion fences (no vmcnt drain, unlike __syncthreads)
__device__ __forceinline__ void barfence() {
    asm volatile("" ::: "memory");
    __builtin_amdgcn_s_barrier();
    asm volatile("" ::: "memory");
}

// ---- fused prep kernel: block-range partitioned, all branches block-uniform ----
// [0,1024):     ctxpart: part[s][b][n] = sum_{k in slice s} ctx[b][k]*W1[1024+k][n]
// [1024,2048):  wconv W1 top half -> W1t (bf16, N-major)
// [2048,3072):  wconv W2          -> W2t
// [3072,5120):  copy obj -> out_obj (fp32) AND obj -> obj_bf (bf16), one pass
__global__ void __launch_bounds__(256) prep_kernel(
    const float* __restrict__ obj, const float* __restrict__ ctx,
    const float* __restrict__ W1, const float* __restrict__ W2,
    unsigned short* __restrict__ W1t, unsigned short* __restrict__ W2t,
    float* __restrict__ part, unsigned short* __restrict__ obj_bf,
    float* __restrict__ out_obj) {
    __shared__ float smem[32 * 33];
    int bid = blockIdx.x;
    int tid = threadIdx.x;

    if (bid < 1024) {
        // ---- ctxpart: 32 b x 8 n-chunks x 4 k-slices; per-thread 128 k-iters ----
        int slice = bid & 3, chunk = (bid >> 2) & 7, b = bid >> 5;
        int nl = tid & 127, kh = tid >> 7;
        int n = chunk * 128 + nl;
        int kbase = slice * 256 + kh * 128;
        const float* c = ctx + (size_t)b * DD + kbase;
        const float* w = W1 + (size_t)(DD + kbase) * DD + n;
        float a0 = 0.f, a1 = 0.f, a2 = 0.f, a3 = 0.f;
#pragma unroll 8
        for (int k = 0; k < 128; k += 4) {
            a0 = fmaf(c[k + 0], w[(size_t)(k + 0) * DD], a0);
            a1 = fmaf(c[k + 1], w[(size_t)(k + 1) * DD], a1);
            a2 = fmaf(c[k + 2], w[(size_t)(k + 2) * DD], a2);
            a3 = fmaf(c[k + 3], w[(size_t)(k + 3) * DD], a3);
        }
        smem[kh * 128 + nl] = (a0 + a1) + (a2 + a3);
        __syncthreads();
        if (kh == 0)
            part[(((size_t)slice * BB + b) << 10) + n] = smem[nl] + smem[128 + nl];
    } else if (bid < 3072) {
        // ---- wconv: 32x32 transpose tiles, fp32 -> bf16 N-major ----
        const float* W = (bid < 2048) ? W1 : W2;
        unsigned short* Wt = (bid < 2048) ? W1t : W2t;
        int t = (bid - 1024) & 1023;
        int k0 = (t >> 5) * 32, n0 = (t & 31) * 32;
        int tr = tid >> 5, tc = tid & 31;
#pragma unroll
        for (int i = 0; i < 4; i++)
            smem[(tr + i * 8) * 33 + tc] = W[(size_t)(k0 + tr + i * 8) * DD + n0 + tc];
        __syncthreads();
#pragma unroll
        for (int i = 0; i < 4; i++)
            Wt[(size_t)(n0 + tr + i * 8) * DD + k0 + tc] = f2bf(smem[tc * 33 + tr + i * 8]);
    } else {
        // ---- copy + bf16-convert: 3200*1024 floats = 819200 float4, one read ----
        const float4* src = (const float4*)obj;
        float4* dst = (float4*)out_obj;
        ushort4* dbf = (ushort4*)obj_bf;
        for (int i = (bid - 3072) * 256 + tid; i < OBJ_ROWS * DD / 4; i += 2048 * 256) {
            float4 v = src[i];
            dst[i] = v;
            ushort4 o;
            o.x = f2bf(v.x); o.y = f2bf(v.y); o.z = f2bf(v.z); o.w = f2bf(v.w);
            dbf[i] = o;
        }
    }
}

// ---- gemmP: blocks [0,200): P = obj_bf @ W1t, 128x128 tile, BK=32, 4 waves
//      (round-6 measured-best structure, 25 m-tiles x 8 n-tiles)
//      blocks [200,232): cbias[b][n] = b1[n] + sum_s part[s][b][n]
// A [3200][1024] bf16 row-major; Bt [1024][1024] bf16 N-major. Out: P bf16.
__global__ void __launch_bounds__(256) gemmP_kernel(
    const unsigned short* __restrict__ A,
    const unsigned short* __restrict__ Bt,
    unsigned short* __restrict__ P,
    const float* __restrict__ part,
    const float* __restrict__ b1,
    float* __restrict__ cbias) {
    constexpr int K = 1024;
    __shared__ __attribute__((aligned(16))) unsigned short As[128 * 32];
    __shared__ __attribute__((aligned(16))) unsigned short Bs[128 * 32];
    int bid = blockIdx.x;
    int tid = threadIdx.x;

    if (bid >= 200) {
        // ---- cbias: one block per batch b ----
        int b = bid - 200;
        float4 v = ((const float4*)b1)[tid];
#pragma unroll
        for (int s = 0; s < 4; s++) {
            float4 p = ((const float4*)(part + (((size_t)s * BB + b) << 10)))[tid];
            v.x += p.x; v.y += p.y; v.z += p.z; v.w += p.w;
        }
        ((float4*)(cbias + ((size_t)b << 10)))[tid] = v;
        return;
    }

    int lane = tid & 63, wave = tid >> 6;
    int wr = wave >> 1, wc = wave & 1;
    int mBase = (bid >> 3) * 128;           // 25 m-tiles
    int nBase = (bid & 7) * 128;            // 8 n-tiles

    f32x4 acc[4][4];
#pragma unroll
    for (int i = 0; i < 4; i++)
#pragma unroll
        for (int j = 0; j < 4; j++) acc[i][j] = (f32x4){0.f, 0.f, 0.f, 0.f};

    const unsigned short* Ab = A + (size_t)mBase * K;
    const unsigned short* Bb = Bt + (size_t)nBase * K;

    for (int k0 = 0; k0 < K; k0 += 32) {
#pragma unroll
        for (int hh = 0; hh < 2; hh++) {
            int c = tid + hh * 256;           // chunk id 0..511
            int row = c >> 2, kc = (c & 3) * 8;
            gld16(Ab + (size_t)row * K + k0 + kc, As + c * 8);
            gld16(Bb + (size_t)row * K + k0 + kc, Bs + c * 8);
        }
        __syncthreads();
        int lr = lane & 15, kg = (lane >> 4) * 8;
        bf16x8 af[4], bfr[4];
#pragma unroll
        for (int m = 0; m < 4; m++)
            af[m] = *(const bf16x8*)&As[(wr * 64 + m * 16 + lr) * 32 + kg];
#pragma unroll
        for (int n = 0; n < 4; n++)
            bfr[n] = *(const bf16x8*)&Bs[(wc * 64 + n * 16 + lr) * 32 + kg];
#pragma unroll
        for (int m = 0; m < 4; m++)
#pragma unroll
            for (int n = 0; n < 4; n++)
                acc[m][n] = __builtin_amdgcn_mfma_f32_16x16x32_bf16(af[m], bfr[n], acc[m][n], 0, 0, 0);
        __syncthreads();
    }

    int lr = lane & 15, rg = (lane >> 4) * 4;
#pragma unroll
    for (int m = 0; m < 4; m++)
#pragma unroll
        for (int n = 0; n < 4; n++) {
            int col = nBase + wc * 64 + n * 16 + lr;
#pragma unroll
            for (int r = 0; r < 4; r++) {
                int row = mBase + wr * 64 + m * 16 + rg + r;
                P[(size_t)row * DD + col] = f2bf(acc[m][n][r]);
            }
        }
}

// ---- hgen: h[row][n] = relu(0.5*(P[i0][n]+P[i1][n]) + cbias[b][n])
// 4 relation-rows per block (round-6 measured-best granularity); thread t owns
// cols [4t,4t+4). cbias precomputed -> 1 bias plane read instead of b1+4 parts.
__global__ void __launch_bounds__(256) hgen_kernel(
    const unsigned short* __restrict__ P, const int* __restrict__ pairs,
    const int* __restrict__ num_obj, const float* __restrict__ cbias,
    unsigned short* __restrict__ h) {
    int rbase = blockIdx.x * 4;           // 4096 blocks
    int b = rbase >> 9;
    int off = 0;
    for (int i = 0; i < b; i++) off += num_obj[i];   // block-uniform, scalar
    int t = threadIdx.x;

    float4 bv = ((const float4*)(cbias + ((size_t)b << 10)))[t];

#pragma unroll
    for (int rr = 0; rr < 4; rr++) {
        int row = rbase + rr;
        int i0 = pairs[2 * row] + off;
        int i1 = pairs[2 * row + 1] + off;
        ushort4 a = ((const ushort4*)(P + (size_t)i0 * DD))[t];
        ushort4 c = ((const ushort4*)(P + (size_t)i1 * DD))[t];
        float v0 = 0.5f * (bf2f(a.x) + bf2f(c.x)) + bv.x;
        float v1 = 0.5f * (bf2f(a.y) + bf2f(c.y)) + bv.y;
        float v2 = 0.5f * (bf2f(a.z) + bf2f(c.z)) + bv.z;
        float v3 = 0.5f * (bf2f(a.w) + bf2f(c.w)) + bv.w;
        ushort4 o;
        o.x = f2bf(v0 > 0.f ? v0 : 0.f);
        o.y = f2bf(v1 > 0.f ? v1 : 0.f);
        o.z = f2bf(v2 > 0.f ? v2 : 0.f);
        o.w = f2bf(v3 > 0.f ? v3 : 0.f);
        ((ushort4*)(h + (size_t)row * DD))[t] = o;
    }
}

// ---- out = relu(h @ W2t + b2): 256x256 tile, BK=64, 8 waves, dbuf LDS,
//      counted vmcnt + raw barriers, XOR swizzle, setprio, XCD swizzle.
//      [round-3 proven structure, byte-for-byte; 42 us / ~818 TF measured]
__global__ void __launch_bounds__(512, 2) gemm2_kernel(
    const unsigned short* __restrict__ A,
    const unsigned short* __restrict__ Bt,
    const float* __restrict__ bias,
    float* __restrict__ Cout) {
    constexpr int K = 1024;
    constexpr int NT = K / 64;   // 16 K-tiles
    extern __shared__ unsigned short lds[];
    int tid = threadIdx.x;
    int lane = tid & 63, wave = tid >> 6;
    int wr = wave >> 2, wc = wave & 3;      // 2 M-waves x 4 N-waves
    int lr = lane & 15, g = lane >> 4;

    // XCD-aware swizzle: 256 blocks, 8 XCDs -> 32 contiguous tiles per XCD (8m x 4n)
    int wg = blockIdx.x;
    int swz = (wg & 7) * 32 + (wg >> 3);
    int mBase = (swz >> 2) * 256;
    int nBase = (swz & 3) * 256;

    const unsigned short* Ab = A + (size_t)mBase * K;
    const unsigned short* Bb = Bt + (size_t)nBase * K;

    int srow[4], soff[4], sdst[4];
#pragma unroll
    for (int i = 0; i < 4; i++) {
        int s = i * 512 + tid;              // 0..2047
        int row = s >> 3, cperm = s & 7;
        srow[i] = row;
        soff[i] = (cperm ^ (row & 7)) * 8;  // source chunk offset (elements)
        sdst[i] = s * 8;                    // linear LDS dest (elements)
    }

    f32x4 acc[8][4];
#pragma unroll
    for (int i = 0; i < 8; i++)
#pragma unroll
        for (int j = 0; j < 4; j++) acc[i][j] = (f32x4){0.f, 0.f, 0.f, 0.f};

    auto STAGE = [&](int bi, int kt) {
        unsigned short* Ad = lds + bi * 16384;
        unsigned short* Bd = lds + 32768 + bi * 16384;
        int ko = kt * 64;
#pragma unroll
        for (int i = 0; i < 4; i++) {
            gld16(Ab + (size_t)srow[i] * K + ko + soff[i], Ad + sdst[i]);
            gld16(Bb + (size_t)srow[i] * K + ko + soff[i], Bd + sdst[i]);
        }
    };

    auto COMPUTE = [&](int bi) {
        const unsigned short* As = lds + bi * 16384;
        const unsigned short* Bs = lds + 32768 + bi * 16384;
        bf16x8 bfr[4][2];
#pragma unroll
        for (int n = 0; n < 4; n++)
#pragma unroll
            for (int kk = 0; kk < 2; kk++) {
                int row = wc * 64 + n * 16 + lr;
                int c = kk * 4 + g;
                bfr[n][kk] = *(const bf16x8*)&Bs[row * 64 + ((c ^ (row & 7)) * 8)];
            }
#pragma unroll
        for (int half = 0; half < 2; half++) {
            bf16x8 af[4][2];
#pragma unroll
            for (int m = 0; m < 4; m++)
#pragma unroll
                for (int kk = 0; kk < 2; kk++) {
                    int row = wr * 128 + (half * 4 + m) * 16 + lr;
                    int c = kk * 4 + g;
                    af[m][kk] = *(const bf16x8*)&As[row * 64 + ((c ^ (row & 7)) * 8)];
                }
            __builtin_amdgcn_s_setprio(1);
#pragma unroll
            for (int m = 0; m < 4; m++)
#pragma unroll
                for (int n = 0; n < 4; n++)
#pragma unroll
                    for (int kk = 0; kk < 2; kk++)
                        acc[half * 4 + m][n] = __builtin_amdgcn_mfma_f32_16x16x32_bf16(
                            af[m][kk], bfr[n][kk], acc[half * 4 + m][n], 0, 0, 0);
            __builtin_amdgcn_s_setprio(0);
        }
    };

    STAGE(0, 0);
    int cur = 0;
    for (int kt = 0; kt < NT - 1; ++kt) {
        STAGE(cur ^ 1, kt + 1);                         // issue next tile's 8 loads
        asm volatile("s_waitcnt vmcnt(8)" ::: "memory"); // oldest 8 (tile kt) landed
        barfence();                                      // all waves' stage(kt) visible
        COMPUTE(cur);
        barfence();                                      // all reads of buf done before overwrite
        cur ^= 1;
    }
    asm volatile("s_waitcnt vmcnt(0)" ::: "memory");
    barfence();
    COMPUTE(cur);

    // epilogue: bias + ReLU + fp32 store
    int rg = g * 4;
#pragma unroll
    for (int m = 0; m < 8; m++) {
#pragma unroll
        for (int n = 0; n < 4; n++) {
            int col = nBase + wc * 64 + n * 16 + lr;
            float bv = bias[col];
#pragma unroll
            for (int r = 0; r < 4; r++) {
                int row = mBase + wr * 128 + m * 16 + rg + r;
                float v = acc[m][n][r] + bv;
                Cout[(size_t)row * 1024 + col] = v > 0.f ? v : 0.f;
            }
        }
    }
}

extern "C" void kernel_launch(void* const* d_in, const int* in_sizes, int n_in,
                              void* d_out, int out_size, void* d_ws, size_t ws_size,
                              hipStream_t stream) {
    (void)in_sizes; (void)n_in; (void)out_size; (void)ws_size;
    const float* obj     = (const float*)d_in[0];
    const float* ctx     = (const float*)d_in[1];
    const int*   num_obj = (const int*)d_in[2];
    // d_in[3] = num_rels (unused by reference math)
    const int*   pairs   = (const int*)d_in[4];
    const float* W1      = (const float*)d_in[5];
    const float* b1      = (const float*)d_in[6];
    const float* W2      = (const float*)d_in[7];
    const float* b2      = (const float*)d_in[8];

    char* ws = (char*)d_ws;
    unsigned short* obj_bf = (unsigned short*)(ws);               // 6,553,600 B
    unsigned short* P      = (unsigned short*)(ws + 6553600);     // 6,553,600 B
    unsigned short* h      = (unsigned short*)(ws + 13107200);    // 33,554,432 B
    unsigned short* W1t    = (unsigned short*)(ws + 46661632);    // 2,097,152 B
    unsigned short* W2t    = (unsigned short*)(ws + 48758784);    // 2,097,152 B
    float*          cbias  = (float*)(ws + 50855936);             // 131,072 B

    float* out_obj = (float*)d_out;
    float* out_f   = out_obj + (size_t)OBJ_ROWS * DD;
    // ctx partial planes [4][32][1024] f32 (512 KB) live in out_f's head:
    // written by prep, read by gemmP's cbias tail blocks, then fully
    // overwritten by gemm2 (strict same-stream ordering; deterministic).
    float* part    = out_f;

    // allow 128 KiB dynamic LDS (host-side, not stream-ordered; graph-capture-safe)
    hipFuncSetAttribute(reinterpret_cast<const void*>(gemm2_kernel),
                        hipFuncAttributeMaxDynamicSharedMemorySize, 131072);

    // 1) fused prep: ctxpart + wconv x2 + (copy obj -> out_obj & obj_bf)
    prep_kernel<<<dim3(5120), 256, 0, stream>>>(
        obj, ctx, W1, W2, W1t, W2t, part, obj_bf, out_obj);
    // 2) P = obj_bf @ W1_top (200 blocks, 128^2 tile) + cbias reduce (32 blocks)
    gemmP_kernel<<<dim3(232), 256, 0, stream>>>(obj_bf, W1t, P, part, b1, cbias);
    // 3) h = relu(0.5*(P[i0]+P[i1]) + cbias)
    hgen_kernel<<<dim3(4096), 256, 0, stream>>>(P, pairs, num_obj, cbias, h);
    // 4) out = relu(h @ W2 + b2)
    gemm2_kernel<<<dim3(256), 512, 131072, stream>>>(h, W2t, b2, out_f);
}

// Round 12
// 89.860 us; speedup vs baseline: 1.0892x; 1.0023x over previous
//
#include <hip/hip_runtime.h>
#include <hip/hip_bf16.h>

// Problem constants (fixed-shape problem)
#define BB   32
#define NREL 512
#define DD   1024
#define MTOT (BB * NREL)      // 16384
#define OBJ_ROWS (BB * 100)   // 3200
#define PPLANE ((size_t)OBJ_ROWS * DD)   // elements per P half-plane

typedef __attribute__((ext_vector_type(8))) short bf16x8;
typedef __attribute__((ext_vector_type(4))) float f32x4;

__device__ __forceinline__ unsigned short f2bf(float f) {
    union { float f; unsigned u; } v; v.f = f;
    unsigned r = v.u + 0x7fff + ((v.u >> 16) & 1);   // RNE
    return (unsigned short)(r >> 16);
}

__device__ __forceinline__ float bf2f(unsigned short s) {
    union { unsigned u; float f; } v; v.u = (unsigned)s << 16;
    return v.f;
}

__device__ __forceinline__ void gld16(const void* g, void* l) {
    __builtin_amdgcn_global_load_lds(
        (const __attribute__((address_space(1))) unsigned int*)g,
        (__attribute__((address_space(3))) unsigned int*)l,
        16, 0, 0);
}

// raw barrier with compiler code-motion fences (no vmcnt drain, unlike __syncthreads)
__device__ __forceinline__ void barfence() {
    asm volatile("" ::: "memory");
    __builtin_amdgcn_s_barrier();
    asm volatile("" ::: "memory");
}

// ---- fused prep kernel: block-range partitioned, all branches block-uniform ----
// [0,1024):     ctxpart: part[s][b][n] = sum_{k in slice s} ctx[b][k]*W1[1024+k][n]
// [1024,2048):  wconv W1 top half -> W1t (bf16, N-major)
// [2048,3072):  wconv W2          -> W2t
// [3072,5120):  copy obj -> out_obj (fp32) AND obj -> obj_bf (bf16), one pass
__global__ void __launch_bounds__(256) prep_kernel(
    const float* __restrict__ obj, const float* __restrict__ ctx,
    const float* __restrict__ W1, const float* __restrict__ W2,
    unsigned short* __restrict__ W1t, unsigned short* __restrict__ W2t,
    float* __restrict__ part, unsigned short* __restrict__ obj_bf,
    float* __restrict__ out_obj) {
    __shared__ float smem[32 * 33];
    int bid = blockIdx.x;
    int tid = threadIdx.x;

    if (bid < 1024) {
        // ---- ctxpart: 32 b x 8 n-chunks x 4 k-slices; per-thread 128 k-iters ----
        int slice = bid & 3, chunk = (bid >> 2) & 7, b = bid >> 5;
        int nl = tid & 127, kh = tid >> 7;
        int n = chunk * 128 + nl;
        int kbase = slice * 256 + kh * 128;
        const float* c = ctx + (size_t)b * DD + kbase;
        const float* w = W1 + (size_t)(DD + kbase) * DD + n;
        float a0 = 0.f, a1 = 0.f, a2 = 0.f, a3 = 0.f;
#pragma unroll 8
        for (int k = 0; k < 128; k += 4) {
            a0 = fmaf(c[k + 0], w[(size_t)(k + 0) * DD], a0);
            a1 = fmaf(c[k + 1], w[(size_t)(k + 1) * DD], a1);
            a2 = fmaf(c[k + 2], w[(size_t)(k + 2) * DD], a2);
            a3 = fmaf(c[k + 3], w[(size_t)(k + 3) * DD], a3);
        }
        smem[kh * 128 + nl] = (a0 + a1) + (a2 + a3);
        __syncthreads();
        if (kh == 0)
            part[(((size_t)slice * BB + b) << 10) + n] = smem[nl] + smem[128 + nl];
    } else if (bid < 3072) {
        // ---- wconv: 32x32 transpose tiles, fp32 -> bf16 N-major ----
        const float* W = (bid < 2048) ? W1 : W2;
        unsigned short* Wt = (bid < 2048) ? W1t : W2t;
        int t = (bid - 1024) & 1023;
        int k0 = (t >> 5) * 32, n0 = (t & 31) * 32;
        int tr = tid >> 5, tc = tid & 31;
#pragma unroll
        for (int i = 0; i < 4; i++)
            smem[(tr + i * 8) * 33 + tc] = W[(size_t)(k0 + tr + i * 8) * DD + n0 + tc];
        __syncthreads();
#pragma unroll
        for (int i = 0; i < 4; i++)
            Wt[(size_t)(n0 + tr + i * 8) * DD + k0 + tc] = f2bf(smem[tc * 33 + tr + i * 8]);
    } else {
        // ---- copy + bf16-convert: 3200*1024 floats = 819200 float4, one read ----
        const float4* src = (const float4*)obj;
        float4* dst = (float4*)out_obj;
        ushort4* dbf = (ushort4*)obj_bf;
        for (int i = (bid - 3072) * 256 + tid; i < OBJ_ROWS * DD / 4; i += 2048 * 256) {
            float4 v = src[i];
            dst[i] = v;
            ushort4 o;
            o.x = f2bf(v.x); o.y = f2bf(v.y); o.z = f2bf(v.z); o.w = f2bf(v.w);
            dbf[i] = o;
        }
    }
}

// ---- gemmP: K-split 2x for occupancy (400 GEMM blocks on 256 CUs).
//   blocks [0,400):  ks = bid/200, tile = bid%200 (25 m x 8 n, 128x128, BK=32):
//                    P[ks][m][n] = obj_bf[m][kslice ks] @ W1t[n][kslice ks]
//   blocks [400,432): cbias[b][n] = b1[n] + sum_s part[s][b][n]
// Tile/sync structure byte-identical to round-6 measured-best; only K range split.
__global__ void __launch_bounds__(256) gemmP_kernel(
    const unsigned short* __restrict__ A,
    const unsigned short* __restrict__ Bt,
    unsigned short* __restrict__ P,
    const float* __restrict__ part,
    const float* __restrict__ b1,
    float* __restrict__ cbias) {
    constexpr int K = 1024;
    __shared__ __attribute__((aligned(16))) unsigned short As[128 * 32];
    __shared__ __attribute__((aligned(16))) unsigned short Bs[128 * 32];
    int bid = blockIdx.x;
    int tid = threadIdx.x;

    if (bid >= 400) {
        // ---- cbias: one block per batch b ----
        int b = bid - 400;
        float4 v = ((const float4*)b1)[tid];
#pragma unroll
        for (int s = 0; s < 4; s++) {
            float4 p = ((const float4*)(part + (((size_t)s * BB + b) << 10)))[tid];
            v.x += p.x; v.y += p.y; v.z += p.z; v.w += p.w;
        }
        ((float4*)(cbias + ((size_t)b << 10)))[tid] = v;
        return;
    }

    int ks = bid / 200;                     // k-slice 0/1
    int t200 = bid - ks * 200;
    int lane = tid & 63, wave = tid >> 6;
    int wr = wave >> 1, wc = wave & 1;
    int mBase = (t200 >> 3) * 128;          // 25 m-tiles
    int nBase = (t200 & 7) * 128;           // 8 n-tiles
    int kLo = ks * 512, kHi = kLo + 512;

    f32x4 acc[4][4];
#pragma unroll
    for (int i = 0; i < 4; i++)
#pragma unroll
        for (int j = 0; j < 4; j++) acc[i][j] = (f32x4){0.f, 0.f, 0.f, 0.f};

    const unsigned short* Ab = A + (size_t)mBase * K;
    const unsigned short* Bb = Bt + (size_t)nBase * K;

    for (int k0 = kLo; k0 < kHi; k0 += 32) {
#pragma unroll
        for (int hh = 0; hh < 2; hh++) {
            int c = tid + hh * 256;           // chunk id 0..511
            int row = c >> 2, kc = (c & 3) * 8;
            gld16(Ab + (size_t)row * K + k0 + kc, As + c * 8);
            gld16(Bb + (size_t)row * K + k0 + kc, Bs + c * 8);
        }
        __syncthreads();
        int lr = lane & 15, kg = (lane >> 4) * 8;
        bf16x8 af[4], bfr[4];
#pragma unroll
        for (int m = 0; m < 4; m++)
            af[m] = *(const bf16x8*)&As[(wr * 64 + m * 16 + lr) * 32 + kg];
#pragma unroll
        for (int n = 0; n < 4; n++)
            bfr[n] = *(const bf16x8*)&Bs[(wc * 64 + n * 16 + lr) * 32 + kg];
#pragma unroll
        for (int m = 0; m < 4; m++)
#pragma unroll
            for (int n = 0; n < 4; n++)
                acc[m][n] = __builtin_amdgcn_mfma_f32_16x16x32_bf16(af[m], bfr[n], acc[m][n], 0, 0, 0);
        __syncthreads();
    }

    unsigned short* Pk = P + (size_t)ks * PPLANE;
    int lr = lane & 15, rg = (lane >> 4) * 4;
#pragma unroll
    for (int m = 0; m < 4; m++)
#pragma unroll
        for (int n = 0; n < 4; n++) {
            int col = nBase + wc * 64 + n * 16 + lr;
#pragma unroll
            for (int r = 0; r < 4; r++) {
                int row = mBase + wr * 64 + m * 16 + rg + r;
                Pk[(size_t)row * DD + col] = f2bf(acc[m][n][r]);
            }
        }
}

// ---- hgen: h[row][n] = relu(0.5*(P0[i0]+P1[i0]+P0[i1]+P1[i1]) + cbias[b][n])
// 4 relation-rows per block; thread t owns cols [4t,4t+4).
__global__ void __launch_bounds__(256) hgen_kernel(
    const unsigned short* __restrict__ P, const int* __restrict__ pairs,
    const int* __restrict__ num_obj, const float* __restrict__ cbias,
    unsigned short* __restrict__ h) {
    int rbase = blockIdx.x * 4;           // 4096 blocks
    int b = rbase >> 9;
    int off = 0;
    for (int i = 0; i < b; i++) off += num_obj[i];   // block-uniform, scalar
    int t = threadIdx.x;

    float4 bv = ((const float4*)(cbias + ((size_t)b << 10)))[t];
    const unsigned short* P1 = P + PPLANE;

#pragma unroll
    for (int rr = 0; rr < 4; rr++) {
        int row = rbase + rr;
        int i0 = pairs[2 * row] + off;
        int i1 = pairs[2 * row + 1] + off;
        ushort4 a0 = ((const ushort4*)(P  + (size_t)i0 * DD))[t];
        ushort4 a1 = ((const ushort4*)(P1 + (size_t)i0 * DD))[t];
        ushort4 c0 = ((const ushort4*)(P  + (size_t)i1 * DD))[t];
        ushort4 c1 = ((const ushort4*)(P1 + (size_t)i1 * DD))[t];
        float v0 = 0.5f * ((bf2f(a0.x) + bf2f(a1.x)) + (bf2f(c0.x) + bf2f(c1.x))) + bv.x;
        float v1 = 0.5f * ((bf2f(a0.y) + bf2f(a1.y)) + (bf2f(c0.y) + bf2f(c1.y))) + bv.y;
        float v2 = 0.5f * ((bf2f(a0.z) + bf2f(a1.z)) + (bf2f(c0.z) + bf2f(c1.z))) + bv.z;
        float v3 = 0.5f * ((bf2f(a0.w) + bf2f(a1.w)) + (bf2f(c0.w) + bf2f(c1.w))) + bv.w;
        ushort4 o;
        o.x = f2bf(v0 > 0.f ? v0 : 0.f);
        o.y = f2bf(v1 > 0.f ? v1 : 0.f);
        o.z = f2bf(v2 > 0.f ? v2 : 0.f);
        o.w = f2bf(v3 > 0.f ? v3 : 0.f);
        ((ushort4*)(h + (size_t)row * DD))[t] = o;
    }
}

// ---- out = relu(h @ W2t + b2): 256x256 tile, BK=64, 8 waves, dbuf LDS,
//      counted vmcnt + raw barriers, XOR swizzle, setprio, XCD swizzle.
//      [round-3 proven structure, byte-for-byte; 42 us / ~818 TF measured]
__global__ void __launch_bounds__(512, 2) gemm2_kernel(
    const unsigned short* __restrict__ A,
    const unsigned short* __restrict__ Bt,
    const float* __restrict__ bias,
    float* __restrict__ Cout) {
    constexpr int K = 1024;
    constexpr int NT = K / 64;   // 16 K-tiles
    extern __shared__ unsigned short lds[];
    int tid = threadIdx.x;
    int lane = tid & 63, wave = tid >> 6;
    int wr = wave >> 2, wc = wave & 3;      // 2 M-waves x 4 N-waves
    int lr = lane & 15, g = lane >> 4;

    // XCD-aware swizzle: 256 blocks, 8 XCDs -> 32 contiguous tiles per XCD (8m x 4n)
    int wg = blockIdx.x;
    int swz = (wg & 7) * 32 + (wg >> 3);
    int mBase = (swz >> 2) * 256;
    int nBase = (swz & 3) * 256;

    const unsigned short* Ab = A + (size_t)mBase * K;
    const unsigned short* Bb = Bt + (size_t)nBase * K;

    int srow[4], soff[4], sdst[4];
#pragma unroll
    for (int i = 0; i < 4; i++) {
        int s = i * 512 + tid;              // 0..2047
        int row = s >> 3, cperm = s & 7;
        srow[i] = row;
        soff[i] = (cperm ^ (row & 7)) * 8;  // source chunk offset (elements)
        sdst[i] = s * 8;                    // linear LDS dest (elements)
    }

    f32x4 acc[8][4];
#pragma unroll
    for (int i = 0; i < 8; i++)
#pragma unroll
        for (int j = 0; j < 4; j++) acc[i][j] = (f32x4){0.f, 0.f, 0.f, 0.f};

    auto STAGE = [&](int bi, int kt) {
        unsigned short* Ad = lds + bi * 16384;
        unsigned short* Bd = lds + 32768 + bi * 16384;
        int ko = kt * 64;
#pragma unroll
        for (int i = 0; i < 4; i++) {
            gld16(Ab + (size_t)srow[i] * K + ko + soff[i], Ad + sdst[i]);
            gld16(Bb + (size_t)srow[i] * K + ko + soff[i], Bd + sdst[i]);
        }
    };

    auto COMPUTE = [&](int bi) {
        const unsigned short* As = lds + bi * 16384;
        const unsigned short* Bs = lds + 32768 + bi * 16384;
        bf16x8 bfr[4][2];
#pragma unroll
        for (int n = 0; n < 4; n++)
#pragma unroll
            for (int kk = 0; kk < 2; kk++) {
                int row = wc * 64 + n * 16 + lr;
                int c = kk * 4 + g;
                bfr[n][kk] = *(const bf16x8*)&Bs[row * 64 + ((c ^ (row & 7)) * 8)];
            }
#pragma unroll
        for (int half = 0; half < 2; half++) {
            bf16x8 af[4][2];
#pragma unroll
            for (int m = 0; m < 4; m++)
#pragma unroll
                for (int kk = 0; kk < 2; kk++) {
                    int row = wr * 128 + (half * 4 + m) * 16 + lr;
                    int c = kk * 4 + g;
                    af[m][kk] = *(const bf16x8*)&As[row * 64 + ((c ^ (row & 7)) * 8)];
                }
            __builtin_amdgcn_s_setprio(1);
#pragma unroll
            for (int m = 0; m < 4; m++)
#pragma unroll
                for (int n = 0; n < 4; n++)
#pragma unroll
                    for (int kk = 0; kk < 2; kk++)
                        acc[half * 4 + m][n] = __builtin_amdgcn_mfma_f32_16x16x32_bf16(
                            af[m][kk], bfr[n][kk], acc[half * 4 + m][n], 0, 0, 0);
            __builtin_amdgcn_s_setprio(0);
        }
    };

    STAGE(0, 0);
    int cur = 0;
    for (int kt = 0; kt < NT - 1; ++kt) {
        STAGE(cur ^ 1, kt + 1);                         // issue next tile's 8 loads
        asm volatile("s_waitcnt vmcnt(8)" ::: "memory"); // oldest 8 (tile kt) landed
        barfence();                                      // all waves' stage(kt) visible
        COMPUTE(cur);
        barfence();                                      // all reads of buf done before overwrite
        cur ^= 1;
    }
    asm volatile("s_waitcnt vmcnt(0)" ::: "memory");
    barfence();
    COMPUTE(cur);

    // epilogue: bias + ReLU + fp32 store
    int rg = g * 4;
#pragma unroll
    for (int m = 0; m < 8; m++) {
#pragma unroll
        for (int n = 0; n < 4; n++) {
            int col = nBase + wc * 64 + n * 16 + lr;
            float bv = bias[col];
#pragma unroll
            for (int r = 0; r < 4; r++) {
                int row = mBase + wr * 128 + m * 16 + rg + r;
                float v = acc[m][n][r] + bv;
                Cout[(size_t)row * 1024 + col] = v > 0.f ? v : 0.f;
            }
        }
    }
}

extern "C" void kernel_launch(void* const* d_in, const int* in_sizes, int n_in,
                              void* d_out, int out_size, void* d_ws, size_t ws_size,
                              hipStream_t stream) {
    (void)in_sizes; (void)n_in; (void)out_size; (void)ws_size;
    const float* obj     = (const float*)d_in[0];
    const float* ctx     = (const float*)d_in[1];
    const int*   num_obj = (const int*)d_in[2];
    // d_in[3] = num_rels (unused by reference math)
    const int*   pairs   = (const int*)d_in[4];
    const float* W1      = (const float*)d_in[5];
    const float* b1      = (const float*)d_in[6];
    const float* W2      = (const float*)d_in[7];
    const float* b2      = (const float*)d_in[8];

    char* ws = (char*)d_ws;
    unsigned short* obj_bf = (unsigned short*)(ws);               // 6,553,600 B
    unsigned short* P      = (unsigned short*)(ws + 6553600);     // 2 planes: 13,107,200 B
    unsigned short* h      = (unsigned short*)(ws + 19660800);    // 33,554,432 B
    unsigned short* W1t    = (unsigned short*)(ws + 53215232);    // 2,097,152 B
    unsigned short* W2t    = (unsigned short*)(ws + 55312384);    // 2,097,152 B
    float*          cbias  = (float*)(ws + 57409536);             // 131,072 B

    float* out_obj = (float*)d_out;
    float* out_f   = out_obj + (size_t)OBJ_ROWS * DD;
    // ctx partial planes [4][32][1024] f32 (512 KB) live in out_f's head:
    // written by prep, read by gemmP's cbias tail blocks, then fully
    // overwritten by gemm2 (strict same-stream ordering; deterministic).
    float* part    = out_f;

    // allow 128 KiB dynamic LDS (host-side, not stream-ordered; graph-capture-safe)
    hipFuncSetAttribute(reinterpret_cast<const void*>(gemm2_kernel),
                        hipFuncAttributeMaxDynamicSharedMemorySize, 131072);

    // 1) fused prep: ctxpart + wconv x2 + (copy obj -> out_obj & obj_bf)
    prep_kernel<<<dim3(5120), 256, 0, stream>>>(
        obj, ctx, W1, W2, W1t, W2t, part, obj_bf, out_obj);
    // 2) P[0/1] = obj_bf @ W1_top k-halves (400 blocks) + cbias reduce (32 blocks)
    gemmP_kernel<<<dim3(432), 256, 0, stream>>>(obj_bf, W1t, P, part, b1, cbias);
    // 3) h = relu(0.5*(P0[i0]+P1[i0]+P0[i1]+P1[i1]) + cbias)
    hgen_kernel<<<dim3(4096), 256, 0, stream>>>(P, pairs, num_obj, cbias, h);
    // 4) out = relu(h @ W2 + b2)
    gemm2_kernel<<<dim3(256), 512, 131072, stream>>>(h, W2t, b2, out_f);
}